// Round 18
// baseline (67.801 us; speedup 1.0000x reference)
//
#include <hip/hip_runtime.h>

// Simple_TensorProduct (e3nn uvw TP, MUL=256, l<=1, v=1) as two fused bf16 GEMMs.
//   out0[z,w]      = sum_k T0[z,k]    * B0[k,w]   (K=512)
//   out1[(z,c),w]  = sum_k T1[(z,c),k]* B1[k,w]   (K=768, M=3N)
//
// R18 = R17 with launch_bounds back to (256,4). R17's aperture fault: the
// (256,5) 102-reg budget forced the allocator to spill/relocate inline-asm
// load destinations while loads were in flight -> landing loads clobbered
// reassigned registers (addresses) -> fault. (256,4)'s 128-reg budget fits
// the ~112 live regs with slack (R16-proven). Kept from R17: LDS 24 KB
// (6 blk/CU cap), cs in {0,2,4,6} stagger, split epilogue (out0 direct,
// out1 LDS-staged coalesced).

typedef short bf16x8 __attribute__((ext_vector_type(8)));
typedef float f32x4 __attribute__((ext_vector_type(4)));
typedef int   ni4   __attribute__((ext_vector_type(4)));
typedef int   ni2   __attribute__((ext_vector_type(2)));

static __device__ __forceinline__ unsigned short f2bf(float f) {
  unsigned int u = __builtin_bit_cast(unsigned int, f);
  u += 0x7FFFu + ((u >> 16) & 1u);   // RNE (prep kernel only)
  return (unsigned short)(u >> 16);
}

// 2x f32 -> packed bf16x2, RNE, single instruction. lo -> D[15:0].
static __device__ __forceinline__ int cvtpk(float lo, float hi) {
  int r;
  asm("v_cvt_pk_bf16_f32 %0, %1, %2" : "=v"(r) : "v"(lo), "v"(hi));
  return r;
}

static __device__ __forceinline__ bf16x8 asbf(int4 v) {
  return __builtin_bit_cast(bf16x8, v);
}
static __device__ __forceinline__ bf16x8 asbfn(ni4 v) {
  return __builtin_bit_cast(bf16x8, v);
}

static __device__ __forceinline__ void gload4(ni4& dst, const void* p) {
  asm volatile("global_load_dwordx4 %0, %1, off" : "=v"(dst) : "v"(p));
}
static __device__ __forceinline__ void gload2(ni2& dst, const void* p) {
  asm volatile("global_load_dwordx2 %0, %1, off" : "=v"(dst) : "v"(p));
}

#define WAITV(n) do { \
    asm volatile("s_waitcnt vmcnt(" #n ")"); \
    __builtin_amdgcn_sched_barrier(0); \
  } while (0)

static __device__ __forceinline__ void phase_barrier() {
  __builtin_amdgcn_sched_barrier(0);
  asm volatile("s_waitcnt lgkmcnt(0)");
  __builtin_amdgcn_sched_barrier(0);
  __builtin_amdgcn_s_barrier();
  __builtin_amdgcn_sched_barrier(0);
}

// ---------------------------------------------------------------------------
// Weight prep (verbatim R12/R13/R16, passed): u-chunk = 32, c in 0..7.
// B1: fid = ((c*3+kt)*16+ct)*64+lane; elem e: kc=kt*32+(lane>>4)*8+e (0..95),
//     seg=kc>>5, u=c*32+(kc&31), w=ct*16+(lane&15)
// B0: fid = 24576 + ((c*2+kt)*16+ct)*64+lane; kc 0..63, seg=kc>>5
// ---------------------------------------------------------------------------
__global__ __launch_bounds__(256) void prep_weights(
    const float* __restrict__ wgt, unsigned short* __restrict__ Bw)
{
  int fid = blockIdx.x * 256 + threadIdx.x;
  union { unsigned short h[8]; int4 v; } pk;
  if (fid < 24576) {
    int lane = fid & 63;
    int ct = (fid >> 6) & 15;
    int q = fid >> 10;            // 0..23 = c*3 + kt
    int kt = q % 3, c = q / 3;
    int w = ct * 16 + (lane & 15);
    int kh = (lane >> 4) * 8;
#pragma unroll
    for (int e = 0; e < 8; ++e) {
      int kc = kt * 32 + kh + e;       // 0..95
      int seg = kc >> 5;
      int u = c * 32 + (kc & 31);
      float s  = (seg == 2) ? 0.025515518153991442f : 0.03608439182435161f;
      int off  = (seg == 0) ? 65536 : (seg == 1 ? 131072 : 262144);
      pk.h[e] = f2bf(wgt[off + u * 256 + w] * s);
    }
    ((int4*)Bw)[fid] = pk.v;
  } else if (fid < 40960) {
    int f2 = fid - 24576;
    int lane = f2 & 63;
    int ct = (f2 >> 6) & 15;
    int q = f2 >> 10;             // 0..15 = c*2 + kt
    int kt = q & 1, c = q >> 1;
    int w = ct * 16 + (lane & 15);
    int kh = (lane >> 4) * 8;
#pragma unroll
    for (int e = 0; e < 8; ++e) {
      int kc = kt * 32 + kh + e;       // 0..63
      int seg = kc >> 5;
      int u = c * 32 + (kc & 31);
      float s  = (seg == 0) ? 0.04419417382415922f : 0.025515518153991442f;
      int off  = (seg == 0) ? 0 : 196608;
      pk.h[e] = f2bf(wgt[off + u * 256 + w] * s);
    }
    ((int4*)Bw)[fid] = pk.v;
  }
}

// Per-buffer LDS map (int4 slots, 704 = 11.25 KB), R12's map (passed):
//   T1: rt*192 + sg*64 + fl   (rt 0..2, sg 0..2)
//   T0: 576 + sg*64 + fl      (sg 0..1)
#define BUFSLOTS 704
#define T0BASE 576

struct X1R2 { ni2 s, v0, v1, v2; };   // s1[2] + v1[2u x 3k] raw bits (4 loads)

static __device__ __forceinline__ void load_x1_2(
    X1R2& r, const float* __restrict__ x1, int zrow, int ub, int rr)
{
  const float* base = x1 + (size_t)zrow * 1024;
  gload2(r.s,  base + ub + rr * 2);
  const float* pv = base + 256 + 3 * ub + rr * 6;
  gload2(r.v0, pv);
  gload2(r.v1, pv + 2);
  gload2(r.v2, pv + 4);
}

// thread (zl = tid>>4 0..15, rr = tid&15) owns u-pair [rr*2, rr*2+2) of the
// 32-u chunk. kt==sg; lane-half lh = rr>>2; dword q = rr&3. (R16, passed)
static __device__ __forceinline__ void build_frags(
    const X1R2& r, int zl, int rr, float s2, const float* v2,
    unsigned int* __restrict__ lds32)
{
  float2 sf = __builtin_bit_cast(float2, r.s);
  float2 va = __builtin_bit_cast(float2, r.v0);
  float2 vb = __builtin_bit_cast(float2, r.v1);
  float2 vc = __builtin_bit_cast(float2, r.v2);
  float s1f[2] = {sf.x, sf.y};
  float vf[6] = {va.x, va.y, vb.x, vb.y, vc.x, vc.y};  // vf[3e+k]
  const int lh = rr >> 2;
  const int q  = rr & 3;

  // ---- T1: sg(=kt) 0..2 x comp k 0..2 ; row = 3*zl + k (0..47)
#pragma unroll
  for (int sg = 0; sg < 3; ++sg) {
#pragma unroll
    for (int k = 0; k < 3; ++k) {
      int row = 3 * zl + k;
      int fl  = (((lh << 4) | (row & 15)) ^ sg) ^ lh;
      int slot = (row >> 4) * 192 + sg * 64 + fl;
      float t0, t1;
      if (sg == 0) {                     // s1 * v2[k]      (-> W2)
        t0 = s1f[0] * v2[k]; t1 = s1f[1] * v2[k];
      } else if (sg == 1) {              // v1[.,k] * s2    (-> W3)
        t0 = vf[k] * s2; t1 = vf[3 + k] * s2;
      } else {                           // (v1 x v2)[k]    (-> W5)
        int k1 = k + 1; if (k1 > 2) k1 -= 3;
        int k2 = k + 2; if (k2 > 2) k2 -= 3;
        t0 = vf[k1] * v2[k2] - vf[k2] * v2[k1];
        t1 = vf[3 + k1] * v2[k2] - vf[3 + k2] * v2[k1];
      }
      lds32[slot * 4 + q] = (unsigned int)cvtpk(t0, t1);
    }
  }
  // ---- T0: sg(=kt) 0..1 ; row = zl
#pragma unroll
  for (int sg = 0; sg < 2; ++sg) {
    int fl = (((lh << 4) | zl) ^ sg) ^ lh;
    int slot = T0BASE + sg * 64 + fl;
    float t0, t1;
    if (sg == 0) {                       // s1 * s2         (-> W1)
      t0 = s1f[0] * s2; t1 = s1f[1] * s2;
    } else {                             // v1 . v2         (-> W4)
      t0 = vf[0] * v2[0] + vf[1] * v2[1] + vf[2] * v2[2];
      t1 = vf[3] * v2[0] + vf[4] * v2[1] + vf[5] * v2[2];
    }
    lds32[slot * 4 + q] = (unsigned int)cvtpk(t0, t1);
  }
}

// Burst-load this wave's per-chunk B slice (asm, static dests): 10 int4.
static __device__ __forceinline__ void burstB(
    ni4 (&vb)[10], const int4* __restrict__ B1v,
    const int4* __restrict__ B0v, int c, int ct0, int lane)
{
#pragma unroll
  for (int kt = 0; kt < 3; ++kt)
#pragma unroll
    for (int j = 0; j < 2; ++j)
      gload4(vb[kt * 2 + j],
             B1v + ((size_t)((c * 3 + kt) * 16 + ct0 + j)) * 64 + lane);
#pragma unroll
  for (int kt = 0; kt < 2; ++kt)
#pragma unroll
    for (int j = 0; j < 2; ++j)
      gload4(vb[6 + kt * 2 + j],
             B0v + ((size_t)((c * 2 + kt) * 16 + ct0 + j)) * 64 + lane);
}

// Pure LDS+MFMA gemm for one u-chunk: 22 MFMA. (verbatim R13/R16, passed)
static __device__ __forceinline__ void gemm_steps(
    const int4* __restrict__ buf, const ni4 (&vb)[10], int lane,
    f32x4 acc1[3][2], f32x4 acc0[2])
{
  __builtin_amdgcn_s_setprio(1);
#pragma unroll
  for (int kt = 0; kt < 3; ++kt) {
    int fl = (lane ^ kt) ^ (lane >> 4);
    int4 a[3];
#pragma unroll
    for (int rt = 0; rt < 3; ++rt) a[rt] = buf[rt * 192 + kt * 64 + fl];
#pragma unroll
    for (int rt = 0; rt < 3; ++rt) {
      bf16x8 av = asbf(a[rt]);
#pragma unroll
      for (int j = 0; j < 2; ++j)
        acc1[rt][j] = __builtin_amdgcn_mfma_f32_16x16x32_bf16(
            av, asbfn(vb[kt * 2 + j]), acc1[rt][j], 0, 0, 0);
    }
  }
#pragma unroll
  for (int kt = 0; kt < 2; ++kt) {
    int fl = (lane ^ kt) ^ (lane >> 4);
    int4 a0 = buf[T0BASE + kt * 64 + fl];
    bf16x8 av = asbf(a0);
#pragma unroll
    for (int j = 0; j < 2; ++j)
      acc0[j] = __builtin_amdgcn_mfma_f32_16x16x32_bf16(
          av, asbfn(vb[6 + kt * 2 + j]), acc0[j], 0, 0, 0);
  }
  __builtin_amdgcn_s_setprio(0);
}

// ---------------------------------------------------------------------------
// Main: 256 thr (4 waves, ct=2 -> 128 cols), w-split (grid 2500), z=16.
// 8 u-chunks of 32, dbuf LDS; chunk order staggered per block (^cs,
// cs in {0,2,4,6}). LDS 24 KB -> 6 blocks/CU cap; bounds(256,4).
// ---------------------------------------------------------------------------
__global__ __launch_bounds__(256, 4) void tp_main(
    const float* __restrict__ x1, const float* __restrict__ x2,
    const int4* __restrict__ B1v, const int4* __restrict__ B0v,
    float* __restrict__ out)
{
  __shared__ int4 ldsT[1536];           // 24576 bytes (T dbuf uses first 1408)
  const int tid  = threadIdx.x;
  const int lane = tid & 63;
  const int wid  = tid >> 6;            // wave 0..3
  const int wh   = blockIdx.x & 1;      // w-half
  const int ct0  = wh * 8 + wid * 2;    // this wave's two 16-col tiles (global)
  const int z0   = (blockIdx.x >> 1) * 16;
  const int zl   = tid >> 4;            // T-build row (0..15)
  const int rr   = tid & 15;            // T-build u-pair (0..15)
  const int cs   = ((blockIdx.x >> 1) & 3) << 1;  // 0/2/4/6: phase stagger

  f32x4 acc1[3][2];
  f32x4 acc0[2];
#pragma unroll
  for (int i = 0; i < 3; ++i)
#pragma unroll
    for (int j = 0; j < 2; ++j) acc1[i][j] = (f32x4){0.f, 0.f, 0.f, 0.f};
#pragma unroll
  for (int j = 0; j < 2; ++j) acc0[j] = (f32x4){0.f, 0.f, 0.f, 0.f};

  // x2 via asm + FULL drain before the pipeline: no compiler VMEM mid-pipe.
  ni4 x2raw;
  gload4(x2raw, x2 + (size_t)(z0 + zl) * 4);
  WAITV(0);
  float4 x2v = __builtin_bit_cast(float4, x2raw);
  const float s2 = x2v.x;
  float v2[3] = {x2v.y, x2v.z, x2v.w};

  unsigned int* lds32_0 = (unsigned int*)ldsT;
  unsigned int* lds32_1 = (unsigned int*)(ldsT + BUFSLOTS);

  X1R2 rA, rB;
  ni4 vb[10];

  // prologue: chunk c0 -> rA, c1 -> rB (8 outstanding); build c0 -> buf0
  load_x1_2(rA, x1, z0 + zl, (0 ^ cs) * 32, rr);
  load_x1_2(rB, x1, z0 + zl, (1 ^ cs) * 32, rr);
  WAITV(4);                              // rA ready
  build_frags(rA, zl, rr, s2, v2, lds32_0);
  phase_barrier();

  // Phase c (0..5): gemm chunk c from BUFG; build chunk c+1 (in RB_) -> BUFB;
  // issue x1 chunk c+2 -> RL_. All names static per phase.
#define PHASE(C, RL_, RB_, BUFB, BUFG) \
  burstB(vb, B1v, B0v, (C) ^ cs, ct0, lane);                    /* -> 14 */ \
  load_x1_2(RL_, x1, z0 + zl, (((C) + 2) ^ cs) * 32, rr);       /* -> 18 */ \
  WAITV(14);                             /* x1(c+1) ready */               \
  build_frags(RB_, zl, rr, s2, v2, BUFB);                                  \
  WAITV(4);                              /* B(c) ready */                  \
  gemm_steps(BUFG, vb, lane, acc1, acc0);                                  \
  phase_barrier();

  PHASE(0, rA, rB, lds32_1, ldsT)             // gemm c0; build c1; load c2
  PHASE(1, rB, rA, lds32_0, ldsT + BUFSLOTS)  // gemm c1; build c2; load c3
  PHASE(2, rA, rB, lds32_1, ldsT)             // gemm c2; build c3; load c4
  PHASE(3, rB, rA, lds32_0, ldsT + BUFSLOTS)  // gemm c3; build c4; load c5
  PHASE(4, rA, rB, lds32_1, ldsT)             // gemm c4; build c5; load c6
  PHASE(5, rB, rA, lds32_0, ldsT + BUFSLOTS)  // gemm c5; build c6; load c7
#undef PHASE

  // ---- phase 6: gemm c6 (buf0); build c7 (rB) -> buf1
  burstB(vb, B1v, B0v, 6 ^ cs, ct0, lane);    // 4 + 10 = 14
  WAITV(10);                             // x1(c7) ready (rB)
  build_frags(rB, zl, rr, s2, v2, lds32_1);
  WAITV(0);                              // B(c6) ready
  gemm_steps(ldsT, vb, lane, acc1, acc0);
  phase_barrier();
  // ---- phase 7: gemm c7 (buf1)
  burstB(vb, B1v, B0v, 7 ^ cs, ct0, lane);
  WAITV(0);
  gemm_steps(ldsT + BUFSLOTS, vb, lane, acc1, acc0);

  // ==== epilogue ====
  // out0 directly from acc (64B-contiguous per 16 lanes; R10's passed path)
  const int col = lane & 15;
  const int rb  = (lane >> 4) * 4;       // C/D: col=lane&15, row=(lane>>4)*4+reg
#pragma unroll
  for (int j = 0; j < 2; ++j) {
    int w = (ct0 + j) * 16 + col;
#pragma unroll
    for (int rg = 0; rg < 4; ++rg) {
      int row = rb + rg;                 // zl 0..15
      out[(size_t)(z0 + row) * 1024 + w] = acc0[j][rg];
    }
  }
  // out1 staged in LDS (24 KB), then coalesced float4 stores (R14, passed)
  phase_barrier();                       // all waves done reading T buffers
  float* ldsF = (float*)ldsT;            // [0,6144): out1 16 x 384
#pragma unroll
  for (int rt = 0; rt < 3; ++rt) {
#pragma unroll
    for (int j = 0; j < 2; ++j) {
      int wl = wid * 32 + j * 16 + col;  // block-local w (0..127)
#pragma unroll
      for (int rg = 0; rg < 4; ++rg) {
        int row = rt * 16 + rb + rg;     // 0..47 ; row = 3*zl + k
        int zz = row / 3;
        int k  = row - zz * 3;
        ldsF[zz * 384 + wl * 3 + k] = acc1[rt][j][rg];
      }
    }
  }
  phase_barrier();                       // stage complete

  const float4* lds4 = (const float4*)ldsF;
#pragma unroll
  for (int i = 0; i < 6; ++i) {
    int idx = i * 256 + tid;             // 0..1535
    int row = idx / 96;
    int c4  = idx - row * 96;
    float4 v = lds4[row * 96 + c4];
    *(float4*)(out + (size_t)(z0 + row) * 1024 + 256 + wh * 384 + c4 * 4) = v;
  }
}

// ---------------------------------------------------------------------------
extern "C" void kernel_launch(void* const* d_in, const int* in_sizes, int n_in,
                              void* d_out, int out_size, void* d_ws, size_t ws_size,
                              hipStream_t stream) {
  const float* x1  = (const float*)d_in[0];   // (n, 1024) f32
  const float* x2  = (const float*)d_in[1];   // (n, 4)    f32
  const float* wgt = (const float*)d_in[2];   // (327680,) f32
  float* out = (float*)d_out;                 // (n, 1024) f32

  // ws: B1 fragments [0, 393216) + B0 fragments [393216, 655360)  (bf16)
  unsigned short* Bw = (unsigned short*)d_ws;
  const int4* B1v = (const int4*)Bw;
  const int4* B0v = B1v + 24576;

  int n = in_sizes[0] / 1024;                 // 20000 (divisible by 16)

  prep_weights<<<160, 256, 0, stream>>>(wgt, Bw);
  tp_main<<<(n / 16) * 2, 256, 0, stream>>>(x1, x2, B1v, B0v, out);
}

// Round 19
// 62.844 us; speedup vs baseline: 1.0789x; 1.0789x over previous
//
#include <hip/hip_runtime.h>

// Simple_TensorProduct (e3nn uvw TP, MUL=256, l<=1, v=1) as two fused bf16 GEMMs.
//   out0[z,w]      = sum_k T0[z,k]    * B0[k,w]   (K=512)
//   out1[(z,c),w]  = sum_k T1[(z,c),k]* B1[k,w]   (K=768, M=3N)
//
// R19 = exact revert to R16 (62.9 us, best measured). R17 (reg-budget 5)
// faulted: allocator relocated in-flight asm-load dests. R18 (24KB LDS +
// out0-direct + finer stagger) regressed to 67.8us: out0 64B half-line
// stores amplified WRITE 80->95MB; occupancy unchanged. R16's verified
// structure: phase-staggered blocks (cs in {0,4}), compiler-proof asm
// pipeline (counted vmcnt, static dests), full LDS-staged coalesced
// epilogue, LDS 32KB, launch_bounds(256,4).

typedef short bf16x8 __attribute__((ext_vector_type(8)));
typedef float f32x4 __attribute__((ext_vector_type(4)));
typedef int   ni4   __attribute__((ext_vector_type(4)));
typedef int   ni2   __attribute__((ext_vector_type(2)));

static __device__ __forceinline__ unsigned short f2bf(float f) {
  unsigned int u = __builtin_bit_cast(unsigned int, f);
  u += 0x7FFFu + ((u >> 16) & 1u);   // RNE (prep kernel only)
  return (unsigned short)(u >> 16);
}

// 2x f32 -> packed bf16x2, RNE, single instruction. lo -> D[15:0].
static __device__ __forceinline__ int cvtpk(float lo, float hi) {
  int r;
  asm("v_cvt_pk_bf16_f32 %0, %1, %2" : "=v"(r) : "v"(lo), "v"(hi));
  return r;
}

static __device__ __forceinline__ bf16x8 asbf(int4 v) {
  return __builtin_bit_cast(bf16x8, v);
}
static __device__ __forceinline__ bf16x8 asbfn(ni4 v) {
  return __builtin_bit_cast(bf16x8, v);
}

static __device__ __forceinline__ void gload4(ni4& dst, const void* p) {
  asm volatile("global_load_dwordx4 %0, %1, off" : "=v"(dst) : "v"(p));
}
static __device__ __forceinline__ void gload2(ni2& dst, const void* p) {
  asm volatile("global_load_dwordx2 %0, %1, off" : "=v"(dst) : "v"(p));
}

#define WAITV(n) do { \
    asm volatile("s_waitcnt vmcnt(" #n ")"); \
    __builtin_amdgcn_sched_barrier(0); \
  } while (0)

static __device__ __forceinline__ void phase_barrier() {
  __builtin_amdgcn_sched_barrier(0);
  asm volatile("s_waitcnt lgkmcnt(0)");
  __builtin_amdgcn_sched_barrier(0);
  __builtin_amdgcn_s_barrier();
  __builtin_amdgcn_sched_barrier(0);
}

// ---------------------------------------------------------------------------
// Weight prep (verbatim R12/R13/R16, passed): u-chunk = 32, c in 0..7.
// B1: fid = ((c*3+kt)*16+ct)*64+lane; elem e: kc=kt*32+(lane>>4)*8+e (0..95),
//     seg=kc>>5, u=c*32+(kc&31), w=ct*16+(lane&15)
// B0: fid = 24576 + ((c*2+kt)*16+ct)*64+lane; kc 0..63, seg=kc>>5
// ---------------------------------------------------------------------------
__global__ __launch_bounds__(256) void prep_weights(
    const float* __restrict__ wgt, unsigned short* __restrict__ Bw)
{
  int fid = blockIdx.x * 256 + threadIdx.x;
  union { unsigned short h[8]; int4 v; } pk;
  if (fid < 24576) {
    int lane = fid & 63;
    int ct = (fid >> 6) & 15;
    int q = fid >> 10;            // 0..23 = c*3 + kt
    int kt = q % 3, c = q / 3;
    int w = ct * 16 + (lane & 15);
    int kh = (lane >> 4) * 8;
#pragma unroll
    for (int e = 0; e < 8; ++e) {
      int kc = kt * 32 + kh + e;       // 0..95
      int seg = kc >> 5;
      int u = c * 32 + (kc & 31);
      float s  = (seg == 2) ? 0.025515518153991442f : 0.03608439182435161f;
      int off  = (seg == 0) ? 65536 : (seg == 1 ? 131072 : 262144);
      pk.h[e] = f2bf(wgt[off + u * 256 + w] * s);
    }
    ((int4*)Bw)[fid] = pk.v;
  } else if (fid < 40960) {
    int f2 = fid - 24576;
    int lane = f2 & 63;
    int ct = (f2 >> 6) & 15;
    int q = f2 >> 10;             // 0..15 = c*2 + kt
    int kt = q & 1, c = q >> 1;
    int w = ct * 16 + (lane & 15);
    int kh = (lane >> 4) * 8;
#pragma unroll
    for (int e = 0; e < 8; ++e) {
      int kc = kt * 32 + kh + e;       // 0..63
      int seg = kc >> 5;
      int u = c * 32 + (kc & 31);
      float s  = (seg == 0) ? 0.04419417382415922f : 0.025515518153991442f;
      int off  = (seg == 0) ? 0 : 196608;
      pk.h[e] = f2bf(wgt[off + u * 256 + w] * s);
    }
    ((int4*)Bw)[fid] = pk.v;
  }
}

// Per-buffer LDS map (int4 slots, 704 = 11.25 KB), R12's map (passed):
//   T1: rt*192 + sg*64 + fl   (rt 0..2, sg 0..2)
//   T0: 576 + sg*64 + fl      (sg 0..1)
#define BUFSLOTS 704
#define T0BASE 576

struct X1R2 { ni2 s, v0, v1, v2; };   // s1[2] + v1[2u x 3k] raw bits (4 loads)

static __device__ __forceinline__ void load_x1_2(
    X1R2& r, const float* __restrict__ x1, int zrow, int ub, int rr)
{
  const float* base = x1 + (size_t)zrow * 1024;
  gload2(r.s,  base + ub + rr * 2);
  const float* pv = base + 256 + 3 * ub + rr * 6;
  gload2(r.v0, pv);
  gload2(r.v1, pv + 2);
  gload2(r.v2, pv + 4);
}

// thread (zl = tid>>4 0..15, rr = tid&15) owns u-pair [rr*2, rr*2+2) of the
// 32-u chunk. kt==sg; lane-half lh = rr>>2; dword q = rr&3. (R16, passed)
static __device__ __forceinline__ void build_frags(
    const X1R2& r, int zl, int rr, float s2, const float* v2,
    unsigned int* __restrict__ lds32)
{
  float2 sf = __builtin_bit_cast(float2, r.s);
  float2 va = __builtin_bit_cast(float2, r.v0);
  float2 vb = __builtin_bit_cast(float2, r.v1);
  float2 vc = __builtin_bit_cast(float2, r.v2);
  float s1f[2] = {sf.x, sf.y};
  float vf[6] = {va.x, va.y, vb.x, vb.y, vc.x, vc.y};  // vf[3e+k]
  const int lh = rr >> 2;
  const int q  = rr & 3;

  // ---- T1: sg(=kt) 0..2 x comp k 0..2 ; row = 3*zl + k (0..47)
#pragma unroll
  for (int sg = 0; sg < 3; ++sg) {
#pragma unroll
    for (int k = 0; k < 3; ++k) {
      int row = 3 * zl + k;
      int fl  = (((lh << 4) | (row & 15)) ^ sg) ^ lh;
      int slot = (row >> 4) * 192 + sg * 64 + fl;
      float t0, t1;
      if (sg == 0) {                     // s1 * v2[k]      (-> W2)
        t0 = s1f[0] * v2[k]; t1 = s1f[1] * v2[k];
      } else if (sg == 1) {              // v1[.,k] * s2    (-> W3)
        t0 = vf[k] * s2; t1 = vf[3 + k] * s2;
      } else {                           // (v1 x v2)[k]    (-> W5)
        int k1 = k + 1; if (k1 > 2) k1 -= 3;
        int k2 = k + 2; if (k2 > 2) k2 -= 3;
        t0 = vf[k1] * v2[k2] - vf[k2] * v2[k1];
        t1 = vf[3 + k1] * v2[k2] - vf[3 + k2] * v2[k1];
      }
      lds32[slot * 4 + q] = (unsigned int)cvtpk(t0, t1);
    }
  }
  // ---- T0: sg(=kt) 0..1 ; row = zl
#pragma unroll
  for (int sg = 0; sg < 2; ++sg) {
    int fl = (((lh << 4) | zl) ^ sg) ^ lh;
    int slot = T0BASE + sg * 64 + fl;
    float t0, t1;
    if (sg == 0) {                       // s1 * s2         (-> W1)
      t0 = s1f[0] * s2; t1 = s1f[1] * s2;
    } else {                             // v1 . v2         (-> W4)
      t0 = vf[0] * v2[0] + vf[1] * v2[1] + vf[2] * v2[2];
      t1 = vf[3] * v2[0] + vf[4] * v2[1] + vf[5] * v2[2];
    }
    lds32[slot * 4 + q] = (unsigned int)cvtpk(t0, t1);
  }
}

// Burst-load this wave's per-chunk B slice (asm, static dests): 10 int4.
static __device__ __forceinline__ void burstB(
    ni4 (&vb)[10], const int4* __restrict__ B1v,
    const int4* __restrict__ B0v, int c, int ct0, int lane)
{
#pragma unroll
  for (int kt = 0; kt < 3; ++kt)
#pragma unroll
    for (int j = 0; j < 2; ++j)
      gload4(vb[kt * 2 + j],
             B1v + ((size_t)((c * 3 + kt) * 16 + ct0 + j)) * 64 + lane);
#pragma unroll
  for (int kt = 0; kt < 2; ++kt)
#pragma unroll
    for (int j = 0; j < 2; ++j)
      gload4(vb[6 + kt * 2 + j],
             B0v + ((size_t)((c * 2 + kt) * 16 + ct0 + j)) * 64 + lane);
}

// Pure LDS+MFMA gemm for one u-chunk: 22 MFMA. (verbatim R13/R16, passed)
static __device__ __forceinline__ void gemm_steps(
    const int4* __restrict__ buf, const ni4 (&vb)[10], int lane,
    f32x4 acc1[3][2], f32x4 acc0[2])
{
  __builtin_amdgcn_s_setprio(1);
#pragma unroll
  for (int kt = 0; kt < 3; ++kt) {
    int fl = (lane ^ kt) ^ (lane >> 4);
    int4 a[3];
#pragma unroll
    for (int rt = 0; rt < 3; ++rt) a[rt] = buf[rt * 192 + kt * 64 + fl];
#pragma unroll
    for (int rt = 0; rt < 3; ++rt) {
      bf16x8 av = asbf(a[rt]);
#pragma unroll
      for (int j = 0; j < 2; ++j)
        acc1[rt][j] = __builtin_amdgcn_mfma_f32_16x16x32_bf16(
            av, asbfn(vb[kt * 2 + j]), acc1[rt][j], 0, 0, 0);
    }
  }
#pragma unroll
  for (int kt = 0; kt < 2; ++kt) {
    int fl = (lane ^ kt) ^ (lane >> 4);
    int4 a0 = buf[T0BASE + kt * 64 + fl];
    bf16x8 av = asbf(a0);
#pragma unroll
    for (int j = 0; j < 2; ++j)
      acc0[j] = __builtin_amdgcn_mfma_f32_16x16x32_bf16(
          av, asbfn(vb[6 + kt * 2 + j]), acc0[j], 0, 0, 0);
  }
  __builtin_amdgcn_s_setprio(0);
}

// ---------------------------------------------------------------------------
// Main: 256 thr (4 waves, ct=2 -> 128 cols), w-split (grid 2500), z=16.
// 8 u-chunks of 32, dbuf LDS; chunk order staggered per block pair (^cs).
// Explicit phases; all asm-load destinations statically named.
// ---------------------------------------------------------------------------
__global__ __launch_bounds__(256, 4) void tp_main(
    const float* __restrict__ x1, const float* __restrict__ x2,
    const int4* __restrict__ B1v, const int4* __restrict__ B0v,
    float* __restrict__ out)
{
  __shared__ int4 ldsT[2048];           // 32768 bytes (T dbuf uses first 1408)
  const int tid  = threadIdx.x;
  const int lane = tid & 63;
  const int wid  = tid >> 6;            // wave 0..3
  const int wh   = blockIdx.x & 1;      // w-half
  const int ct0  = wh * 8 + wid * 2;    // this wave's two 16-col tiles (global)
  const int z0   = (blockIdx.x >> 1) * 16;
  const int zl   = tid >> 4;            // T-build row (0..15)
  const int rr   = tid & 15;            // T-build u-pair (0..15)
  const int cs   = (blockIdx.x & 2) << 1;  // 0 or 4: phase stagger

  f32x4 acc1[3][2];
  f32x4 acc0[2];
#pragma unroll
  for (int i = 0; i < 3; ++i)
#pragma unroll
    for (int j = 0; j < 2; ++j) acc1[i][j] = (f32x4){0.f, 0.f, 0.f, 0.f};
#pragma unroll
  for (int j = 0; j < 2; ++j) acc0[j] = (f32x4){0.f, 0.f, 0.f, 0.f};

  // x2 via asm + FULL drain before the pipeline: no compiler VMEM mid-pipe.
  ni4 x2raw;
  gload4(x2raw, x2 + (size_t)(z0 + zl) * 4);
  WAITV(0);
  float4 x2v = __builtin_bit_cast(float4, x2raw);
  const float s2 = x2v.x;
  float v2[3] = {x2v.y, x2v.z, x2v.w};

  unsigned int* lds32_0 = (unsigned int*)ldsT;
  unsigned int* lds32_1 = (unsigned int*)(ldsT + BUFSLOTS);

  X1R2 rA, rB;
  ni4 vb[10];

  // prologue: chunk c0 -> rA, c1 -> rB (8 outstanding); build c0 -> buf0
  load_x1_2(rA, x1, z0 + zl, (0 ^ cs) * 32, rr);
  load_x1_2(rB, x1, z0 + zl, (1 ^ cs) * 32, rr);
  WAITV(4);                              // rA ready
  build_frags(rA, zl, rr, s2, v2, lds32_0);
  phase_barrier();

  // Phase c (0..5): gemm chunk c from BUFG; build chunk c+1 (in RB_) -> BUFB;
  // issue x1 chunk c+2 -> RL_. All names static per phase.
#define PHASE(C, RL_, RB_, BUFB, BUFG) \
  burstB(vb, B1v, B0v, (C) ^ cs, ct0, lane);                    /* -> 14 */ \
  load_x1_2(RL_, x1, z0 + zl, (((C) + 2) ^ cs) * 32, rr);       /* -> 18 */ \
  WAITV(14);                             /* x1(c+1) ready */               \
  build_frags(RB_, zl, rr, s2, v2, BUFB);                                  \
  WAITV(4);                              /* B(c) ready */                  \
  gemm_steps(BUFG, vb, lane, acc1, acc0);                                  \
  phase_barrier();

  PHASE(0, rA, rB, lds32_1, ldsT)             // gemm c0; build c1; load c2
  PHASE(1, rB, rA, lds32_0, ldsT + BUFSLOTS)  // gemm c1; build c2; load c3
  PHASE(2, rA, rB, lds32_1, ldsT)             // gemm c2; build c3; load c4
  PHASE(3, rB, rA, lds32_0, ldsT + BUFSLOTS)  // gemm c3; build c4; load c5
  PHASE(4, rA, rB, lds32_1, ldsT)             // gemm c4; build c5; load c6
  PHASE(5, rB, rA, lds32_0, ldsT + BUFSLOTS)  // gemm c5; build c6; load c7
#undef PHASE

  // ---- phase 6: gemm c6 (buf0); build c7 (rB) -> buf1
  burstB(vb, B1v, B0v, 6 ^ cs, ct0, lane);    // 4 + 10 = 14
  WAITV(10);                             // x1(c7) ready (rB)
  build_frags(rB, zl, rr, s2, v2, lds32_1);
  WAITV(0);                              // B(c6) ready
  gemm_steps(ldsT, vb, lane, acc1, acc0);
  phase_barrier();
  // ---- phase 7: gemm c7 (buf1)
  burstB(vb, B1v, B0v, 7 ^ cs, ct0, lane);
  WAITV(0);
  gemm_steps(ldsT + BUFSLOTS, vb, lane, acc1, acc0);

  // ==== epilogue: stage in LDS, store coalesced (verbatim R14/R16) ====
  phase_barrier();                       // all waves done reading T buffers
  float* ldsF = (float*)ldsT;            // [0,6144) out1 16x384; [6144,8192) out0
  const int col = lane & 15;
  const int rb  = (lane >> 4) * 4;       // C/D: col=lane&15, row=(lane>>4)*4+reg
#pragma unroll
  for (int j = 0; j < 2; ++j) {
    int wl = wid * 32 + j * 16 + col;    // block-local w (0..127)
#pragma unroll
    for (int rg = 0; rg < 4; ++rg) {
      int row = rb + rg;                 // zl 0..15
      ldsF[6144 + row * 128 + wl] = acc0[j][rg];
    }
  }
#pragma unroll
  for (int rt = 0; rt < 3; ++rt) {
#pragma unroll
    for (int j = 0; j < 2; ++j) {
      int wl = wid * 32 + j * 16 + col;
#pragma unroll
      for (int rg = 0; rg < 4; ++rg) {
        int row = rt * 16 + rb + rg;     // 0..47 ; row = 3*zl + k
        int zz = row / 3;
        int k  = row - zz * 3;
        ldsF[zz * 384 + wl * 3 + k] = acc1[rt][j][rg];
      }
    }
  }
  phase_barrier();                       // stage complete

  const float4* lds4 = (const float4*)ldsF;
#pragma unroll
  for (int i = 0; i < 6; ++i) {
    int idx = i * 256 + tid;             // 0..1535
    int row = idx / 96;
    int c4  = idx - row * 96;
    float4 v = lds4[row * 96 + c4];
    *(float4*)(out + (size_t)(z0 + row) * 1024 + 256 + wh * 384 + c4 * 4) = v;
  }
#pragma unroll
  for (int i = 0; i < 2; ++i) {
    int idx = i * 256 + tid;             // 0..511
    int row = idx >> 5;
    int c4  = idx & 31;
    float4 v = lds4[1536 + row * 32 + c4];
    *(float4*)(out + (size_t)(z0 + row) * 1024 + wh * 128 + c4 * 4) = v;
  }
}

// ---------------------------------------------------------------------------
extern "C" void kernel_launch(void* const* d_in, const int* in_sizes, int n_in,
                              void* d_out, int out_size, void* d_ws, size_t ws_size,
                              hipStream_t stream) {
  const float* x1  = (const float*)d_in[0];   // (n, 1024) f32
  const float* x2  = (const float*)d_in[1];   // (n, 4)    f32
  const float* wgt = (const float*)d_in[2];   // (327680,) f32
  float* out = (float*)d_out;                 // (n, 1024) f32

  // ws: B1 fragments [0, 393216) + B0 fragments [393216, 655360)  (bf16)
  unsigned short* Bw = (unsigned short*)d_ws;
  const int4* B1v = (const int4*)Bw;
  const int4* B0v = B1v + 24576;

  int n = in_sizes[0] / 1024;                 // 20000 (divisible by 16)

  prep_weights<<<160, 256, 0, stream>>>(wgt, Bw);
  tp_main<<<(n / 16) * 2, 256, 0, stream>>>(x1, x2, B1v, B0v, out);
}

// Round 21
// 62.840 us; speedup vs baseline: 1.0790x; 1.0001x over previous
//
#include <hip/hip_runtime.h>

// Simple_TensorProduct (e3nn uvw TP, MUL=256, l<=1, v=1) as two fused bf16 GEMMs.
//   out0[z,w]      = sum_k T0[z,k]    * B0[k,w]   (K=512)
//   out1[(z,c),w]  = sum_k T1[(z,c),k]* B1[k,w]   (K=768, M=3N)
//
// FINAL = R16/R19 (62.8-62.9 us, reproduced twice). Structure:
//  - weights pre-converted to prescaled bf16 MFMA B-fragments (d_ws)
//  - per z-tile, x2 folded into x1 on the fly -> bf16 A-fragments in LDS
//  - 8 u-chunks of 32, double-buffered LDS, compiler-proof asm pipeline
//    (asm global loads w/ static dests + hand-counted vmcnt + sched_barrier)
//  - phase-staggered co-resident blocks (cs in {0,4}) so blocks cover each
//    other's B-load stalls  (+12% -- the decisive lever, R16)
//  - fully LDS-staged coalesced epilogue (+3.5%, R14)
// Falsified levers: B-reg dbuf (R20: reg pressure faults), tighter bounds
// (R17: faults), 24KB LDS + direct out0 stores (R18: write amplification),
// zero-barrier waves (R12: flat), nt-hints (R9: worse), occupancy extremes
// (R13: FETCH blowup). 62.8us = latency-structure plateau; no pipe >37%.

typedef short bf16x8 __attribute__((ext_vector_type(8)));
typedef float f32x4 __attribute__((ext_vector_type(4)));
typedef int   ni4   __attribute__((ext_vector_type(4)));
typedef int   ni2   __attribute__((ext_vector_type(2)));

static __device__ __forceinline__ unsigned short f2bf(float f) {
  unsigned int u = __builtin_bit_cast(unsigned int, f);
  u += 0x7FFFu + ((u >> 16) & 1u);   // RNE (prep kernel only)
  return (unsigned short)(u >> 16);
}

// 2x f32 -> packed bf16x2, RNE, single instruction. lo -> D[15:0].
static __device__ __forceinline__ int cvtpk(float lo, float hi) {
  int r;
  asm("v_cvt_pk_bf16_f32 %0, %1, %2" : "=v"(r) : "v"(lo), "v"(hi));
  return r;
}

static __device__ __forceinline__ bf16x8 asbf(int4 v) {
  return __builtin_bit_cast(bf16x8, v);
}
static __device__ __forceinline__ bf16x8 asbfn(ni4 v) {
  return __builtin_bit_cast(bf16x8, v);
}

static __device__ __forceinline__ void gload4(ni4& dst, const void* p) {
  asm volatile("global_load_dwordx4 %0, %1, off" : "=v"(dst) : "v"(p));
}
static __device__ __forceinline__ void gload2(ni2& dst, const void* p) {
  asm volatile("global_load_dwordx2 %0, %1, off" : "=v"(dst) : "v"(p));
}

#define WAITV(n) do { \
    asm volatile("s_waitcnt vmcnt(" #n ")"); \
    __builtin_amdgcn_sched_barrier(0); \
  } while (0)

static __device__ __forceinline__ void phase_barrier() {
  __builtin_amdgcn_sched_barrier(0);
  asm volatile("s_waitcnt lgkmcnt(0)");
  __builtin_amdgcn_sched_barrier(0);
  __builtin_amdgcn_s_barrier();
  __builtin_amdgcn_sched_barrier(0);
}

// ---------------------------------------------------------------------------
// Weight prep: u-chunk = 32, c in 0..7, kt==seg.
// B1: fid = ((c*3+kt)*16+ct)*64+lane; elem e: kc=kt*32+(lane>>4)*8+e (0..95),
//     seg=kc>>5, u=c*32+(kc&31), w=ct*16+(lane&15)
// B0: fid = 24576 + ((c*2+kt)*16+ct)*64+lane; kc 0..63, seg=kc>>5
// ---------------------------------------------------------------------------
__global__ __launch_bounds__(256) void prep_weights(
    const float* __restrict__ wgt, unsigned short* __restrict__ Bw)
{
  int fid = blockIdx.x * 256 + threadIdx.x;
  union { unsigned short h[8]; int4 v; } pk;
  if (fid < 24576) {
    int lane = fid & 63;
    int ct = (fid >> 6) & 15;
    int q = fid >> 10;            // 0..23 = c*3 + kt
    int kt = q % 3, c = q / 3;
    int w = ct * 16 + (lane & 15);
    int kh = (lane >> 4) * 8;
#pragma unroll
    for (int e = 0; e < 8; ++e) {
      int kc = kt * 32 + kh + e;       // 0..95
      int seg = kc >> 5;
      int u = c * 32 + (kc & 31);
      float s  = (seg == 2) ? 0.025515518153991442f : 0.03608439182435161f;
      int off  = (seg == 0) ? 65536 : (seg == 1 ? 131072 : 262144);
      pk.h[e] = f2bf(wgt[off + u * 256 + w] * s);
    }
    ((int4*)Bw)[fid] = pk.v;
  } else if (fid < 40960) {
    int f2 = fid - 24576;
    int lane = f2 & 63;
    int ct = (f2 >> 6) & 15;
    int q = f2 >> 10;             // 0..15 = c*2 + kt
    int kt = q & 1, c = q >> 1;
    int w = ct * 16 + (lane & 15);
    int kh = (lane >> 4) * 8;
#pragma unroll
    for (int e = 0; e < 8; ++e) {
      int kc = kt * 32 + kh + e;       // 0..63
      int seg = kc >> 5;
      int u = c * 32 + (kc & 31);
      float s  = (seg == 0) ? 0.04419417382415922f : 0.025515518153991442f;
      int off  = (seg == 0) ? 0 : 196608;
      pk.h[e] = f2bf(wgt[off + u * 256 + w] * s);
    }
    ((int4*)Bw)[fid] = pk.v;
  }
}

// Per-buffer LDS map (int4 slots, 704 = 11.25 KB):
//   T1: rt*192 + sg*64 + fl   (rt 0..2, sg 0..2)
//   T0: 576 + sg*64 + fl      (sg 0..1)
#define BUFSLOTS 704
#define T0BASE 576

struct X1R2 { ni2 s, v0, v1, v2; };   // s1[2] + v1[2u x 3k] raw bits (4 loads)

static __device__ __forceinline__ void load_x1_2(
    X1R2& r, const float* __restrict__ x1, int zrow, int ub, int rr)
{
  const float* base = x1 + (size_t)zrow * 1024;
  gload2(r.s,  base + ub + rr * 2);
  const float* pv = base + 256 + 3 * ub + rr * 6;
  gload2(r.v0, pv);
  gload2(r.v1, pv + 2);
  gload2(r.v2, pv + 4);
}

// thread (zl = tid>>4 0..15, rr = tid&15) owns u-pair [rr*2, rr*2+2) of the
// 32-u chunk. kt==sg; lane-half lh = rr>>2; dword q = rr&3.
static __device__ __forceinline__ void build_frags(
    const X1R2& r, int zl, int rr, float s2, const float* v2,
    unsigned int* __restrict__ lds32)
{
  float2 sf = __builtin_bit_cast(float2, r.s);
  float2 va = __builtin_bit_cast(float2, r.v0);
  float2 vb = __builtin_bit_cast(float2, r.v1);
  float2 vc = __builtin_bit_cast(float2, r.v2);
  float s1f[2] = {sf.x, sf.y};
  float vf[6] = {va.x, va.y, vb.x, vb.y, vc.x, vc.y};  // vf[3e+k]
  const int lh = rr >> 2;
  const int q  = rr & 3;

  // ---- T1: sg(=kt) 0..2 x comp k 0..2 ; row = 3*zl + k (0..47)
#pragma unroll
  for (int sg = 0; sg < 3; ++sg) {
#pragma unroll
    for (int k = 0; k < 3; ++k) {
      int row = 3 * zl + k;
      int fl  = (((lh << 4) | (row & 15)) ^ sg) ^ lh;
      int slot = (row >> 4) * 192 + sg * 64 + fl;
      float t0, t1;
      if (sg == 0) {                     // s1 * v2[k]      (-> W2)
        t0 = s1f[0] * v2[k]; t1 = s1f[1] * v2[k];
      } else if (sg == 1) {              // v1[.,k] * s2    (-> W3)
        t0 = vf[k] * s2; t1 = vf[3 + k] * s2;
      } else {                           // (v1 x v2)[k]    (-> W5)
        int k1 = k + 1; if (k1 > 2) k1 -= 3;
        int k2 = k + 2; if (k2 > 2) k2 -= 3;
        t0 = vf[k1] * v2[k2] - vf[k2] * v2[k1];
        t1 = vf[3 + k1] * v2[k2] - vf[3 + k2] * v2[k1];
      }
      lds32[slot * 4 + q] = (unsigned int)cvtpk(t0, t1);
    }
  }
  // ---- T0: sg(=kt) 0..1 ; row = zl
#pragma unroll
  for (int sg = 0; sg < 2; ++sg) {
    int fl = (((lh << 4) | zl) ^ sg) ^ lh;
    int slot = T0BASE + sg * 64 + fl;
    float t0, t1;
    if (sg == 0) {                       // s1 * s2         (-> W1)
      t0 = s1f[0] * s2; t1 = s1f[1] * s2;
    } else {                             // v1 . v2         (-> W4)
      t0 = vf[0] * v2[0] + vf[1] * v2[1] + vf[2] * v2[2];
      t1 = vf[3] * v2[0] + vf[4] * v2[1] + vf[5] * v2[2];
    }
    lds32[slot * 4 + q] = (unsigned int)cvtpk(t0, t1);
  }
}

// Burst-load this wave's per-chunk B slice (asm, static dests): 10 int4.
static __device__ __forceinline__ void burstB(
    ni4 (&vb)[10], const int4* __restrict__ B1v,
    const int4* __restrict__ B0v, int c, int ct0, int lane)
{
#pragma unroll
  for (int kt = 0; kt < 3; ++kt)
#pragma unroll
    for (int j = 0; j < 2; ++j)
      gload4(vb[kt * 2 + j],
             B1v + ((size_t)((c * 3 + kt) * 16 + ct0 + j)) * 64 + lane);
#pragma unroll
  for (int kt = 0; kt < 2; ++kt)
#pragma unroll
    for (int j = 0; j < 2; ++j)
      gload4(vb[6 + kt * 2 + j],
             B0v + ((size_t)((c * 2 + kt) * 16 + ct0 + j)) * 64 + lane);
}

// Pure LDS+MFMA gemm for one u-chunk: 22 MFMA.
static __device__ __forceinline__ void gemm_steps(
    const int4* __restrict__ buf, const ni4 (&vb)[10], int lane,
    f32x4 acc1[3][2], f32x4 acc0[2])
{
  __builtin_amdgcn_s_setprio(1);
#pragma unroll
  for (int kt = 0; kt < 3; ++kt) {
    int fl = (lane ^ kt) ^ (lane >> 4);
    int4 a[3];
#pragma unroll
    for (int rt = 0; rt < 3; ++rt) a[rt] = buf[rt * 192 + kt * 64 + fl];
#pragma unroll
    for (int rt = 0; rt < 3; ++rt) {
      bf16x8 av = asbf(a[rt]);
#pragma unroll
      for (int j = 0; j < 2; ++j)
        acc1[rt][j] = __builtin_amdgcn_mfma_f32_16x16x32_bf16(
            av, asbfn(vb[kt * 2 + j]), acc1[rt][j], 0, 0, 0);
    }
  }
#pragma unroll
  for (int kt = 0; kt < 2; ++kt) {
    int fl = (lane ^ kt) ^ (lane >> 4);
    int4 a0 = buf[T0BASE + kt * 64 + fl];
    bf16x8 av = asbf(a0);
#pragma unroll
    for (int j = 0; j < 2; ++j)
      acc0[j] = __builtin_amdgcn_mfma_f32_16x16x32_bf16(
          av, asbfn(vb[6 + kt * 2 + j]), acc0[j], 0, 0, 0);
  }
  __builtin_amdgcn_s_setprio(0);
}

// ---------------------------------------------------------------------------
// Main: 256 thr (4 waves, ct=2 -> 128 cols), w-split (grid 2500), z=16.
// 8 u-chunks of 32, dbuf LDS; chunk order staggered per block pair (^cs).
// Explicit phases; all asm-load destinations statically named.
// ---------------------------------------------------------------------------
__global__ __launch_bounds__(256, 4) void tp_main(
    const float* __restrict__ x1, const float* __restrict__ x2,
    const int4* __restrict__ B1v, const int4* __restrict__ B0v,
    float* __restrict__ out)
{
  __shared__ int4 ldsT[2048];           // 32768 bytes (T dbuf uses first 1408)
  const int tid  = threadIdx.x;
  const int lane = tid & 63;
  const int wid  = tid >> 6;            // wave 0..3
  const int wh   = blockIdx.x & 1;      // w-half
  const int ct0  = wh * 8 + wid * 2;    // this wave's two 16-col tiles (global)
  const int z0   = (blockIdx.x >> 1) * 16;
  const int zl   = tid >> 4;            // T-build row (0..15)
  const int rr   = tid & 15;            // T-build u-pair (0..15)
  const int cs   = (blockIdx.x & 2) << 1;  // 0 or 4: phase stagger

  f32x4 acc1[3][2];
  f32x4 acc0[2];
#pragma unroll
  for (int i = 0; i < 3; ++i)
#pragma unroll
    for (int j = 0; j < 2; ++j) acc1[i][j] = (f32x4){0.f, 0.f, 0.f, 0.f};
#pragma unroll
  for (int j = 0; j < 2; ++j) acc0[j] = (f32x4){0.f, 0.f, 0.f, 0.f};

  // x2 via asm + FULL drain before the pipeline: no compiler VMEM mid-pipe.
  ni4 x2raw;
  gload4(x2raw, x2 + (size_t)(z0 + zl) * 4);
  WAITV(0);
  float4 x2v = __builtin_bit_cast(float4, x2raw);
  const float s2 = x2v.x;
  float v2[3] = {x2v.y, x2v.z, x2v.w};

  unsigned int* lds32_0 = (unsigned int*)ldsT;
  unsigned int* lds32_1 = (unsigned int*)(ldsT + BUFSLOTS);

  X1R2 rA, rB;
  ni4 vb[10];

  // prologue: chunk c0 -> rA, c1 -> rB (8 outstanding); build c0 -> buf0
  load_x1_2(rA, x1, z0 + zl, (0 ^ cs) * 32, rr);
  load_x1_2(rB, x1, z0 + zl, (1 ^ cs) * 32, rr);
  WAITV(4);                              // rA ready
  build_frags(rA, zl, rr, s2, v2, lds32_0);
  phase_barrier();

  // Phase c (0..5): gemm chunk c from BUFG; build chunk c+1 (in RB_) -> BUFB;
  // issue x1 chunk c+2 -> RL_. All names static per phase.
#define PHASE(C, RL_, RB_, BUFB, BUFG) \
  burstB(vb, B1v, B0v, (C) ^ cs, ct0, lane);                    /* -> 14 */ \
  load_x1_2(RL_, x1, z0 + zl, (((C) + 2) ^ cs) * 32, rr);       /* -> 18 */ \
  WAITV(14);                             /* x1(c+1) ready */               \
  build_frags(RB_, zl, rr, s2, v2, BUFB);                                  \
  WAITV(4);                              /* B(c) ready */                  \
  gemm_steps(BUFG, vb, lane, acc1, acc0);                                  \
  phase_barrier();

  PHASE(0, rA, rB, lds32_1, ldsT)             // gemm c0; build c1; load c2
  PHASE(1, rB, rA, lds32_0, ldsT + BUFSLOTS)  // gemm c1; build c2; load c3
  PHASE(2, rA, rB, lds32_1, ldsT)             // gemm c2; build c3; load c4
  PHASE(3, rB, rA, lds32_0, ldsT + BUFSLOTS)  // gemm c3; build c4; load c5
  PHASE(4, rA, rB, lds32_1, ldsT)             // gemm c4; build c5; load c6
  PHASE(5, rB, rA, lds32_0, ldsT + BUFSLOTS)  // gemm c5; build c6; load c7
#undef PHASE

  // ---- phase 6: gemm c6 (buf0); build c7 (rB) -> buf1
  burstB(vb, B1v, B0v, 6 ^ cs, ct0, lane);    // 4 + 10 = 14
  WAITV(10);                             // x1(c7) ready (rB)
  build_frags(rB, zl, rr, s2, v2, lds32_1);
  WAITV(0);                              // B(c6) ready
  gemm_steps(ldsT, vb, lane, acc1, acc0);
  phase_barrier();
  // ---- phase 7: gemm c7 (buf1)
  burstB(vb, B1v, B0v, 7 ^ cs, ct0, lane);
  WAITV(0);
  gemm_steps(ldsT + BUFSLOTS, vb, lane, acc1, acc0);

  // ==== epilogue: stage in LDS, store coalesced ====
  phase_barrier();                       // all waves done reading T buffers
  float* ldsF = (float*)ldsT;            // [0,6144) out1 16x384; [6144,8192) out0
  const int col = lane & 15;
  const int rb  = (lane >> 4) * 4;       // C/D: col=lane&15, row=(lane>>4)*4+reg
#pragma unroll
  for (int j = 0; j < 2; ++j) {
    int wl = wid * 32 + j * 16 + col;    // block-local w (0..127)
#pragma unroll
    for (int rg = 0; rg < 4; ++rg) {
      int row = rb + rg;                 // zl 0..15
      ldsF[6144 + row * 128 + wl] = acc0[j][rg];
    }
  }
#pragma unroll
  for (int rt = 0; rt < 3; ++rt) {
#pragma unroll
    for (int j = 0; j < 2; ++j) {
      int wl = wid * 32 + j * 16 + col;
#pragma unroll
      for (int rg = 0; rg < 4; ++rg) {
        int row = rt * 16 + rb + rg;     // 0..47 ; row = 3*zl + k
        int zz = row / 3;
        int k  = row - zz * 3;
        ldsF[zz * 384 + wl * 3 + k] = acc1[rt][j][rg];
      }
    }
  }
  phase_barrier();                       // stage complete

  const float4* lds4 = (const float4*)ldsF;
#pragma unroll
  for (int i = 0; i < 6; ++i) {
    int idx = i * 256 + tid;             // 0..1535
    int row = idx / 96;
    int c4  = idx - row * 96;
    float4 v = lds4[row * 96 + c4];
    *(float4*)(out + (size_t)(z0 + row) * 1024 + 256 + wh * 384 + c4 * 4) = v;
  }
#pragma unroll
  for (int i = 0; i < 2; ++i) {
    int idx = i * 256 + tid;             // 0..511
    int row = idx >> 5;
    int c4  = idx & 31;
    float4 v = lds4[1536 + row * 32 + c4];
    *(float4*)(out + (size_t)(z0 + row) * 1024 + wh * 128 + c4 * 4) = v;
  }
}

// ---------------------------------------------------------------------------
extern "C" void kernel_launch(void* const* d_in, const int* in_sizes, int n_in,
                              void* d_out, int out_size, void* d_ws, size_t ws_size,
                              hipStream_t stream) {
  const float* x1  = (const float*)d_in[0];   // (n, 1024) f32
  const float* x2  = (const float*)d_in[1];   // (n, 4)    f32
  const float* wgt = (const float*)d_in[2];   // (327680,) f32
  float* out = (float*)d_out;                 // (n, 1024) f32

  // ws: B1 fragments [0, 393216) + B0 fragments [393216, 655360)  (bf16)
  unsigned short* Bw = (unsigned short*)d_ws;
  const int4* B1v = (const int4*)Bw;
  const int4* B0v = B1v + 24576;

  int n = in_sizes[0] / 1024;                 // 20000 (divisible by 16)

  prep_weights<<<160, 256, 0, stream>>>(wgt, Bw);
  tp_main<<<(n / 16) * 2, 256, 0, stream>>>(x1, x2, B1v, B0v, out);
}